// Round 1
// baseline (154.837 us; speedup 1.0000x reference)
//
#include <hip/hip_runtime.h>
#include <hip/hip_bf16.h>
#include <math.h>

#define S_LEN 2048
#define D_DIM 256
#define WIN 33
#define HALF 16

// One wave (64 lanes) per query row. Lane l owns D elements [4l, 4l+4).
// 4 waves per 256-thread block -> 4 consecutive rows per block (window overlap
// gives L1/L2 locality).
__global__ __launch_bounds__(256) void local_attn_kernel(
    const float* __restrict__ q,
    const float* __restrict__ k,
    const float* __restrict__ v,
    const int*   __restrict__ mask,
    float* __restrict__ out_v,   // [B*S*D]
    float* __restrict__ out_p)   // [B*S*WIN]
{
    const int lane = threadIdx.x & 63;
    const int wave = threadIdx.x >> 6;
    const int row  = blockIdx.x * 4 + wave;      // 0 .. B*S-1
    const int b    = row >> 11;                  // S = 2048
    const int s    = row & (S_LEN - 1);

    const float4* qv = (const float4*)(q + (size_t)row * D_DIM);
    const float4  qr = qv[lane];

    const float scale = 1.0f / 16.0f;            // 1/sqrt(256)
    float scores[WIN];

    // ---- QK^T over the window ----
#pragma unroll
    for (int j = 0; j < WIN; ++j) {
        const int idx   = s - HALF + j;
        const bool valid = (idx >= 0) && (idx < S_LEN);
        const int idxc  = min(max(idx, 0), S_LEN - 1);
        const float4* kv = (const float4*)(k + ((size_t)b * S_LEN + idxc) * D_DIM);
        const float4 kr = kv[lane];
        float part = qr.x * kr.x + qr.y * kr.y + qr.z * kr.z + qr.w * kr.w;
        // 64-lane butterfly sum; every lane ends with the full dot product.
#pragma unroll
        for (int off = 32; off > 0; off >>= 1)
            part += __shfl_xor(part, off, 64);
        const bool mvalid = valid && (mask[b * S_LEN + idxc] != 0);
        scores[j] = mvalid ? part * scale : -1e10f;
    }

    // ---- softmax over 33 (all lanes redundantly; registers only) ----
    float m = scores[0];
#pragma unroll
    for (int j = 1; j < WIN; ++j) m = fmaxf(m, scores[j]);
    float l = 0.0f;
#pragma unroll
    for (int j = 0; j < WIN; ++j) {
        scores[j] = __expf(scores[j] - m);
        l += scores[j];
    }
    const float rinv = 1.0f / l;

    // ---- PV + grab this lane's p for the coalesced p_attn store ----
    float4 o = make_float4(0.f, 0.f, 0.f, 0.f);
    float my_p = 0.0f;
#pragma unroll
    for (int j = 0; j < WIN; ++j) {
        const float pj = scores[j] * rinv;
        if (lane == j) my_p = pj;                // static j -> cndmask, no scratch
        const int idx  = s - HALF + j;
        const int idxc = min(max(idx, 0), S_LEN - 1);
        const float4* vv = (const float4*)(v + ((size_t)b * S_LEN + idxc) * D_DIM);
        const float4 vr = vv[lane];
        o.x += pj * vr.x; o.y += pj * vr.y; o.z += pj * vr.z; o.w += pj * vr.w;
    }

    float4* ov = (float4*)(out_v + (size_t)row * D_DIM);
    ov[lane] = o;
    if (lane < WIN)
        out_p[(size_t)row * WIN + lane] = my_p;
}

extern "C" void kernel_launch(void* const* d_in, const int* in_sizes, int n_in,
                              void* d_out, int out_size, void* d_ws, size_t ws_size,
                              hipStream_t stream) {
    const float* q    = (const float*)d_in[0];
    const float* k    = (const float*)d_in[1];
    const float* v    = (const float*)d_in[2];
    const int*   mask = (const int*)d_in[3];

    const int B = 4;
    float* out_v = (float*)d_out;                          // B*S*D floats
    float* out_p = (float*)d_out + (size_t)B * S_LEN * D_DIM; // then B*S*WIN

    const int rows = B * S_LEN;            // 8192
    const int blocks = rows / 4;           // 4 waves (rows) per block
    local_attn_kernel<<<blocks, 256, 0, stream>>>(q, k, v, mask, out_v, out_p);
}

// Round 3
// 84.322 us; speedup vs baseline: 1.8363x; 1.8363x over previous
//
#include <hip/hip_runtime.h>
#include <math.h>

#define S_LEN 2048
#define D_DIM 256
#define WIN 33
#define HALF 16
#define PT_STRIDE 72   // shorts; 144 B rows -> 2-way bank aliasing (free)

typedef __attribute__((ext_vector_type(8))) short short8_t;  // 8 bf16 MFMA frag
typedef __attribute__((ext_vector_type(4))) float f32x4;

__device__ inline unsigned short f32_to_bf16(float f) {
    unsigned u = __float_as_uint(f);
    return (unsigned short)((u + 0x7fffu + ((u >> 16) & 1u)) >> 16);  // RNE
}

__device__ inline short8_t pack_bf16x8(float4 a, float4 b) {
    short8_t r;
    r[0] = (short)f32_to_bf16(a.x); r[1] = (short)f32_to_bf16(a.y);
    r[2] = (short)f32_to_bf16(a.z); r[3] = (short)f32_to_bf16(a.w);
    r[4] = (short)f32_to_bf16(b.x); r[5] = (short)f32_to_bf16(b.y);
    r[6] = (short)f32_to_bf16(b.z); r[7] = (short)f32_to_bf16(b.w);
    return r;
}

// Block = 16 query rows, 128 threads = 2 waves.
// Wave 0 (h=0): QK^T (global->reg bf16 frags), in-register softmax, p_attn
//               store, P -> small LDS slab.  ONE __syncthreads().
// Both waves:   PV, wave h handles output dims [128h, 128h+128).
__global__ __launch_bounds__(128) void local_attn_wv(
    const float* __restrict__ q,
    const float* __restrict__ k,
    const float* __restrict__ v,
    const int*   __restrict__ mask,
    float* __restrict__ out_v,   // [B*S*D]
    float* __restrict__ out_p)   // [B*S*WIN]
{
    __shared__ __align__(16) unsigned short Pt[16 * PT_STRIDE];  // 2.3 KB

    const int t    = threadIdx.x;
    const int lane = t & 63;
    const int h    = t >> 6;          // wave id: 0 or 1
    const int l15  = lane & 15;
    const int q4   = lane >> 4;

    const int tile = blockIdx.x;          // 0..511
    const int b    = tile >> 7;           // 128 tiles per batch
    const int s0   = (tile & 127) << 4;   // first query row (in batch)

    const float* qb = q + ((size_t)b * S_LEN + s0) * D_DIM;
    const float* kb = k + (size_t)b * S_LEN * D_DIM;
    const float* vb = v + (size_t)b * S_LEN * D_DIM;

    if (h == 0) {
        // ---- per-lane span columns: 3 col-tiles of 16 (span = 48) ----
        int  krow[3]; bool mv[3];
#pragma unroll
        for (int ct = 0; ct < 3; ++ct) {
            const int kv    = s0 - HALF + ct * 16 + l15;
            const bool valid = (kv >= 0) && (kv < S_LEN);
            const int kc    = min(max(kv, 0), S_LEN - 1);
            krow[ct] = kc;
            mv[ct]   = valid && (mask[b * S_LEN + kc] != 0);
        }
        // ---- Q A-fragments: A[m=l15][k=q4*8+j], 8 k-steps ----
        short8_t aq[8];
#pragma unroll
        for (int ks = 0; ks < 8; ++ks) {
            const float* p = qb + l15 * D_DIM + ks * 32 + q4 * 8;
            const float4 x = *(const float4*)p;
            const float4 y = *(const float4*)(p + 4);
            aq[ks] = pack_bf16x8(x, y);
        }
        // ---- QK^T: 3 col-tiles x 8 k-steps ----
        f32x4 acc[3];
        acc[0] = (f32x4){0.f,0.f,0.f,0.f};
        acc[1] = (f32x4){0.f,0.f,0.f,0.f};
        acc[2] = (f32x4){0.f,0.f,0.f,0.f};
#pragma unroll
        for (int ct = 0; ct < 3; ++ct) {
            const float* kr = kb + (size_t)krow[ct] * D_DIM;
#pragma unroll
            for (int ks = 0; ks < 8; ++ks) {
                const float* p = kr + ks * 32 + q4 * 8;
                const float4 x = *(const float4*)p;
                const float4 y = *(const float4*)(p + 4);
                const short8_t bk = pack_bf16x8(x, y);
                acc[ct] = __builtin_amdgcn_mfma_f32_16x16x32_bf16(aq[ks], bk, acc[ct], 0, 0, 0);
            }
        }
        // ---- band + mask (C layout: row m = q4*4+r, col c = ct*16+l15) ----
        float sv[3][4];
#pragma unroll
        for (int ct = 0; ct < 3; ++ct)
#pragma unroll
            for (int r = 0; r < 4; ++r) {
                const int m = q4 * 4 + r;
                const int c = ct * 16 + l15;
                const int j = c - m;                       // window offset
                const bool inband = (j >= 0) && (j < WIN);
                const float s = acc[ct][r] * 0.0625f;      // 1/sqrt(256)
                sv[ct][r] = inband ? (mv[ct] ? s : -1e10f) : -1e30f;
            }
        // ---- softmax per row r: reduce across the quad's 16 lanes ----
        float rmax[4], rinv[4];
#pragma unroll
        for (int r = 0; r < 4; ++r) {
            float m = fmaxf(fmaxf(sv[0][r], sv[1][r]), sv[2][r]);
            m = fmaxf(m, __shfl_xor(m, 1, 64));
            m = fmaxf(m, __shfl_xor(m, 2, 64));
            m = fmaxf(m, __shfl_xor(m, 4, 64));
            m = fmaxf(m, __shfl_xor(m, 8, 64));
            rmax[r] = m;
        }
#pragma unroll
        for (int ct = 0; ct < 3; ++ct)
#pragma unroll
            for (int r = 0; r < 4; ++r)
                sv[ct][r] = __expf(sv[ct][r] - rmax[r]);   // out-of-band -> 0
#pragma unroll
        for (int r = 0; r < 4; ++r) {
            float s = sv[0][r] + sv[1][r] + sv[2][r];
            s += __shfl_xor(s, 1, 64);
            s += __shfl_xor(s, 2, 64);
            s += __shfl_xor(s, 4, 64);
            s += __shfl_xor(s, 8, 64);
            rinv[r] = 1.0f / s;
        }
        // ---- P -> LDS (bf16) + p_attn store (f32, from registers) ----
#pragma unroll
        for (int ct = 0; ct < 3; ++ct)
#pragma unroll
            for (int r = 0; r < 4; ++r) {
                const int m = q4 * 4 + r;
                const int c = ct * 16 + l15;
                const float p = sv[ct][r] * rinv[r];
                Pt[m * PT_STRIDE + c] = f32_to_bf16(p);
                const int j = c - m;
                if (j >= 0 && j < WIN)
                    out_p[((size_t)(b * S_LEN + s0 + m)) * WIN + j] = p;
            }
        // zero-pad P columns 48..63 (k-padding for the 2nd PV k-step)
#pragma unroll
        for (int r = 0; r < 4; ++r)
            Pt[(q4 * 4 + r) * PT_STRIDE + 48 + l15] = 0;
    }
    __syncthreads();

    // ---------------- PV: out(16 x 128) for this wave's D-half --------------
    short8_t ap[2];
#pragma unroll
    for (int ks = 0; ks < 2; ++ks)
        ap[ks] = *(const short8_t*)&Pt[l15 * PT_STRIDE + ks * 32 + q4 * 8];

    const float* vrow[2][8];
#pragma unroll
    for (int ks = 0; ks < 2; ++ks)
#pragma unroll
        for (int j = 0; j < 8; ++j) {
            const int g  = ks * 32 + q4 * 8 + j;
            const int kv = min(max(s0 - HALF + g, 0), S_LEN - 1);
            vrow[ks][j] = vb + (size_t)kv * D_DIM + h * 128;
        }

    f32x4 acc[8];
#pragma unroll
    for (int nt = 0; nt < 8; ++nt) acc[nt] = (f32x4){0.f,0.f,0.f,0.f};
#pragma unroll
    for (int nt = 0; nt < 8; ++nt) {
        const int d = nt * 16 + l15;
#pragma unroll
        for (int ks = 0; ks < 2; ++ks) {
            float4 x, y;
            x.x = vrow[ks][0][d]; x.y = vrow[ks][1][d];
            x.z = vrow[ks][2][d]; x.w = vrow[ks][3][d];
            y.x = vrow[ks][4][d]; y.y = vrow[ks][5][d];
            y.z = vrow[ks][6][d]; y.w = vrow[ks][7][d];
            const short8_t bv = pack_bf16x8(x, y);
            acc[nt] = __builtin_amdgcn_mfma_f32_16x16x32_bf16(ap[ks], bv, acc[nt], 0, 0, 0);
        }
    }
    float* ob = out_v + ((size_t)b * S_LEN + s0) * D_DIM + h * 128;
#pragma unroll
    for (int nt = 0; nt < 8; ++nt)
#pragma unroll
        for (int r = 0; r < 4; ++r)
            ob[(size_t)(q4 * 4 + r) * D_DIM + nt * 16 + l15] = acc[nt][r];
}

extern "C" void kernel_launch(void* const* d_in, const int* in_sizes, int n_in,
                              void* d_out, int out_size, void* d_ws, size_t ws_size,
                              hipStream_t stream) {
    const float* q    = (const float*)d_in[0];
    const float* k    = (const float*)d_in[1];
    const float* v    = (const float*)d_in[2];
    const int*   mask = (const int*)d_in[3];

    const int B = 4;
    float* out_v = (float*)d_out;
    float* out_p = (float*)d_out + (size_t)B * S_LEN * D_DIM;

    const int blocks = B * (S_LEN / 16);    // 512 blocks of 128 threads
    local_attn_wv<<<blocks, 128, 0, stream>>>(q, k, v, mask, out_v, out_p);
}